// Round 2
// baseline (509.643 us; speedup 1.0000x reference)
//
#include <hip/hip_runtime.h>
#include <hip/hip_bf16.h>

// TemporalLinearAttention: out = ((softmax_d(q)*s) @ k_sm^T @ v) @ w_out
// with qkv = x @ w_qkv, k_sm = softmax_n(k).  Reassociated (q@k^T)@v.
//
// Pipeline: conv_x, conv_w -> gemm_qkv (bf16 MFMA) -> attn (per-(b,h) wave)
//           -> gemm_out (bf16 MFMA, f32 out)
// ws layout note: attn ALIASES xb (xb dead after gemm_qkv) -> ~258 MiB total.

typedef __attribute__((ext_vector_type(8))) short bf16x8;
typedef __attribute__((ext_vector_type(4))) float f32x4;

__device__ __forceinline__ unsigned short f2bf(float f) {
  __hip_bfloat16 h = __float2bfloat16(f);
  return __builtin_bit_cast(unsigned short, h);
}
__device__ __forceinline__ float bf2f(unsigned short u) {
  unsigned int v = ((unsigned int)u) << 16;
  return __builtin_bit_cast(float, v);
}
__device__ __forceinline__ void gload16(const void* g, void* l) {
  __builtin_amdgcn_global_load_lds(
      (__attribute__((address_space(1))) void*)g,
      (__attribute__((address_space(3))) void*)l, 16, 0, 0);
}

// ---------------- conversions ----------------
__global__ __launch_bounds__(256) void conv_x_k(const float* __restrict__ x,
                                                unsigned short* __restrict__ xb) {
  size_t i = ((size_t)blockIdx.x * 256 + threadIdx.x) * 8;  // 16384 blocks exact
  float4 a = *(const float4*)(x + i);
  float4 b = *(const float4*)(x + i + 4);
  union { unsigned short u[8]; bf16x8 v; } o;
  o.u[0] = f2bf(a.x); o.u[1] = f2bf(a.y); o.u[2] = f2bf(a.z); o.u[3] = f2bf(a.w);
  o.u[4] = f2bf(b.x); o.u[5] = f2bf(b.y); o.u[6] = f2bf(b.z); o.u[7] = f2bf(b.w);
  *(bf16x8*)(xb + i) = o.v;
}

// wqt[n][k] = bf16(w_qkv[k][n])  (1536x512), wot[n][k] = bf16(w_out[k][n]) (512x512)
__global__ __launch_bounds__(256) void conv_w_k(const float* __restrict__ wq,
                                                const float* __restrict__ wo,
                                                unsigned short* __restrict__ wqt,
                                                unsigned short* __restrict__ wot) {
  int i = blockIdx.x * 256 + threadIdx.x;  // 4096 blocks = 1,048,576 exact
  if (i < 786432) {
    int n = i >> 9, k = i & 511;
    wqt[i] = f2bf(wq[k * 1536 + n]);
  } else {
    int j = i - 786432;
    int n = j >> 9, k = j & 511;
    wot[j] = f2bf(wo[k * 512 + n]);
  }
}

// ---------------- qkv GEMM: [65536,512] x [512,1536] -> bf16 [65536,1536] ----------------
// m97 structure: 128x128 tile, 4 waves (2x2), 16x16x32 bf16 MFMA, global_load_lds staging.
__global__ __launch_bounds__(256) void gemm_qkv_k(const unsigned short* __restrict__ A,
                                                  const unsigned short* __restrict__ B,
                                                  unsigned short* __restrict__ C) {
  __shared__ __align__(16) unsigned short As[128 * 32];
  __shared__ __align__(16) unsigned short Bs[128 * 32];
  int orig = blockIdx.x;                      // 6144 blocks
  int local = orig >> 3;                      // XCD-chunked: 12 N-tiles of one M-tile
  int mtile = (orig & 7) * 64 + local / 12;   // stay on one XCD -> A-tile L2 reuse
  int ntile = local % 12;
  int m0 = mtile * 128, n0 = ntile * 128;
  int tid = threadIdx.x, w = tid >> 6, l = tid & 63;
  int wr = w >> 1, wc = w & 1;

  f32x4 z4 = {0.f, 0.f, 0.f, 0.f};
  f32x4 acc[4][4];
#pragma unroll
  for (int i = 0; i < 4; ++i)
#pragma unroll
    for (int j = 0; j < 4; ++j) acc[i][j] = z4;

  const unsigned short* ga0 = A + (size_t)(m0 + w * 32 + (l >> 2)) * 512 + (l & 3) * 8;
  const unsigned short* gb0 = B + (size_t)(n0 + w * 32 + (l >> 2)) * 512 + (l & 3) * 8;
  unsigned short* lA = &As[(w * 32) * 32];
  unsigned short* lB = &Bs[(w * 32) * 32];

  for (int kb = 0; kb < 16; ++kb) {
    if (kb) __syncthreads();
    const unsigned short* ga = ga0 + kb * 32;
    const unsigned short* gb = gb0 + kb * 32;
    gload16(ga, lA);
    gload16(ga + 16 * 512, lA + 16 * 32);
    gload16(gb, lB);
    gload16(gb + 16 * 512, lB + 16 * 32);
    __syncthreads();  // compiler drains vmcnt before s_barrier

    bf16x8 af[4], bfr[4];
#pragma unroll
    for (int mt = 0; mt < 4; ++mt)
      af[mt] = *(const bf16x8*)&As[(wr * 64 + mt * 16 + (l & 15)) * 32 + (l >> 4) * 8];
#pragma unroll
    for (int nt = 0; nt < 4; ++nt)
      bfr[nt] = *(const bf16x8*)&Bs[(wc * 64 + nt * 16 + (l & 15)) * 32 + (l >> 4) * 8];
#pragma unroll
    for (int mt = 0; mt < 4; ++mt)
#pragma unroll
      for (int nt = 0; nt < 4; ++nt)
        acc[mt][nt] = __builtin_amdgcn_mfma_f32_16x16x32_bf16(af[mt], bfr[nt], acc[mt][nt], 0, 0, 0);
  }

  // C/D layout: col = lane&15, row = (lane>>4)*4 + reg
#pragma unroll
  for (int mt = 0; mt < 4; ++mt)
#pragma unroll
    for (int nt = 0; nt < 4; ++nt)
#pragma unroll
      for (int r = 0; r < 4; ++r) {
        int row = m0 + wr * 64 + mt * 16 + (l >> 4) * 4 + r;
        int col = n0 + wc * 64 + nt * 16 + (l & 15);
        C[(size_t)row * 1536 + col] = f2bf(acc[mt][nt][r]);
      }
}

// ---------------- attention: per (b,h) wave ----------------
// q,k,v = qkv[b*16.., {0,512,1024}+h*64..]; q softmax over d (lanes), k softmax over n
// (in-lane); S = q@k^T (K=64, 2 MFMAs); out = S@v (K=16 zero-padded to 32).
#define QOFF 0
#define KOFF 1152
#define VOFF 2304
#define SOFF 3328
__global__ __launch_bounds__(256) void attn_k(const unsigned short* __restrict__ qkv,
                                              unsigned short* __restrict__ attn) {
  __shared__ __align__(16) unsigned short lds[4 * 3584];
  int tid = threadIdx.x, wid = tid >> 6, l = tid & 63;
  int p = blockIdx.x * 4 + wid;  // 8192 blocks -> 32768 (b,h) pairs
  int b = p >> 3, h = p & 7;
  unsigned short* W = &lds[wid * 3584];
  const size_t rowb = (size_t)(b * 16) * 1536;

  // k: lane = column d; softmax over 16 frames in-lane
  float kv[16];
#pragma unroll
  for (int n = 0; n < 16; ++n) kv[n] = bf2f(qkv[rowb + n * 1536 + 512 + h * 64 + l]);
  float km = kv[0];
#pragma unroll
  for (int n = 1; n < 16; ++n) km = fmaxf(km, kv[n]);
  float ks = 0.f;
#pragma unroll
  for (int n = 0; n < 16; ++n) { kv[n] = __expf(kv[n] - km); ks += kv[n]; }
  float kinv = 1.f / ks;
#pragma unroll
  for (int n = 0; n < 16; ++n) W[KOFF + n * 72 + l] = f2bf(kv[n] * kinv);

  // q: lane = column d; softmax over d = full-wave reduce per row, then * SCALE
#pragma unroll
  for (int n = 0; n < 16; ++n) {
    float x = bf2f(qkv[rowb + n * 1536 + h * 64 + l]);
    float mx = x;
    mx = fmaxf(mx, __shfl_xor(mx, 1));  mx = fmaxf(mx, __shfl_xor(mx, 2));
    mx = fmaxf(mx, __shfl_xor(mx, 4));  mx = fmaxf(mx, __shfl_xor(mx, 8));
    mx = fmaxf(mx, __shfl_xor(mx, 16)); mx = fmaxf(mx, __shfl_xor(mx, 32));
    float e = __expf(x - mx);
    float s = e;
    s += __shfl_xor(s, 1);  s += __shfl_xor(s, 2);  s += __shfl_xor(s, 4);
    s += __shfl_xor(s, 8);  s += __shfl_xor(s, 16); s += __shfl_xor(s, 32);
    W[QOFF + n * 72 + l] = f2bf(e / s * 0.125f);
  }

  // v: load [n][e] rows, store transposed v_tr[e][n] for B-frag reads
  const unsigned short* vp = qkv + rowb + (size_t)(l >> 2) * 1536 + 1024 + h * 64 + (l & 3) * 16;
  bf16x8 v0 = *(const bf16x8*)vp;
  bf16x8 v1 = *(const bf16x8*)(vp + 8);
#pragma unroll
  for (int c = 0; c < 8; ++c)
    W[VOFF + ((l & 3) * 16 + c) * 16 + (l >> 2)] = (unsigned short)v0[c];
#pragma unroll
  for (int c = 0; c < 8; ++c)
    W[VOFF + ((l & 3) * 16 + 8 + c) * 16 + (l >> 2)] = (unsigned short)v1[c];
  __syncthreads();

  // S = q_sm @ k_sm^T : A,B frags have identical addressing ([row][d-contig])
  f32x4 sacc = {0.f, 0.f, 0.f, 0.f};
#pragma unroll
  for (int kb = 0; kb < 2; ++kb) {
    bf16x8 a  = *(const bf16x8*)&W[QOFF + (l & 15) * 72 + kb * 32 + (l >> 4) * 8];
    bf16x8 bb = *(const bf16x8*)&W[KOFF + (l & 15) * 72 + kb * 32 + (l >> 4) * 8];
    sacc = __builtin_amdgcn_mfma_f32_16x16x32_bf16(a, bb, sacc, 0, 0, 0);
  }
#pragma unroll
  for (int r = 0; r < 4; ++r)
    W[SOFF + ((l >> 4) * 4 + r) * 16 + (l & 15)] = f2bf(sacc[r]);
  __syncthreads();

  // out = S @ v  (K = 16 frames, zero-padded to 32: lanes >=32 contribute zeros)
  bf16x8 zz = {0, 0, 0, 0, 0, 0, 0, 0};
  bf16x8 sa = zz;
  if (l < 32) sa = *(const bf16x8*)&W[SOFF + (l & 15) * 16 + (l >> 4) * 8];
#pragma unroll
  for (int et = 0; et < 4; ++et) {
    bf16x8 vb = zz;
    if (l < 32) vb = *(const bf16x8*)&W[VOFF + (et * 16 + (l & 15)) * 16 + (l >> 4) * 8];
    f32x4 o = {0.f, 0.f, 0.f, 0.f};
    o = __builtin_amdgcn_mfma_f32_16x16x32_bf16(sa, vb, o, 0, 0, 0);
#pragma unroll
    for (int r = 0; r < 4; ++r)
      attn[(size_t)(b * 16 + (l >> 4) * 4 + r) * 512 + h * 64 + et * 16 + (l & 15)] = f2bf(o[r]);
  }
}

// ---------------- output GEMM: [65536,512] x [512,512] -> f32 ----------------
__global__ __launch_bounds__(256) void gemm_out_k(const unsigned short* __restrict__ A,
                                                  const unsigned short* __restrict__ B,
                                                  float* __restrict__ C) {
  __shared__ __align__(16) unsigned short As[128 * 32];
  __shared__ __align__(16) unsigned short Bs[128 * 32];
  int orig = blockIdx.x;  // 2048
  int local = orig >> 3;
  int mtile = (orig & 7) * 64 + local / 4;
  int ntile = local % 4;
  int m0 = mtile * 128, n0 = ntile * 128;
  int tid = threadIdx.x, w = tid >> 6, l = tid & 63;
  int wr = w >> 1, wc = w & 1;

  f32x4 z4 = {0.f, 0.f, 0.f, 0.f};
  f32x4 acc[4][4];
#pragma unroll
  for (int i = 0; i < 4; ++i)
#pragma unroll
    for (int j = 0; j < 4; ++j) acc[i][j] = z4;

  const unsigned short* ga0 = A + (size_t)(m0 + w * 32 + (l >> 2)) * 512 + (l & 3) * 8;
  const unsigned short* gb0 = B + (size_t)(n0 + w * 32 + (l >> 2)) * 512 + (l & 3) * 8;
  unsigned short* lA = &As[(w * 32) * 32];
  unsigned short* lB = &Bs[(w * 32) * 32];

  for (int kb = 0; kb < 16; ++kb) {
    if (kb) __syncthreads();
    const unsigned short* ga = ga0 + kb * 32;
    const unsigned short* gb = gb0 + kb * 32;
    gload16(ga, lA);
    gload16(ga + 16 * 512, lA + 16 * 32);
    gload16(gb, lB);
    gload16(gb + 16 * 512, lB + 16 * 32);
    __syncthreads();

    bf16x8 af[4], bfr[4];
#pragma unroll
    for (int mt = 0; mt < 4; ++mt)
      af[mt] = *(const bf16x8*)&As[(wr * 64 + mt * 16 + (l & 15)) * 32 + (l >> 4) * 8];
#pragma unroll
    for (int nt = 0; nt < 4; ++nt)
      bfr[nt] = *(const bf16x8*)&Bs[(wc * 64 + nt * 16 + (l & 15)) * 32 + (l >> 4) * 8];
#pragma unroll
    for (int mt = 0; mt < 4; ++mt)
#pragma unroll
      for (int nt = 0; nt < 4; ++nt)
        acc[mt][nt] = __builtin_amdgcn_mfma_f32_16x16x32_bf16(af[mt], bfr[nt], acc[mt][nt], 0, 0, 0);
  }

#pragma unroll
  for (int mt = 0; mt < 4; ++mt)
#pragma unroll
    for (int nt = 0; nt < 4; ++nt)
#pragma unroll
      for (int r = 0; r < 4; ++r) {
        int row = m0 + wr * 64 + mt * 16 + (l >> 4) * 4 + r;
        int col = n0 + wc * 64 + nt * 16 + (l & 15);
        C[(size_t)row * 512 + col] = acc[mt][nt][r];
      }
}

extern "C" void kernel_launch(void* const* d_in, const int* in_sizes, int n_in,
                              void* d_out, int out_size, void* d_ws, size_t ws_size,
                              hipStream_t stream) {
  const float* x  = (const float*)d_in[0];   // [4096,16,512]
  const float* wq = (const float*)d_in[1];   // [512,1536]
  const float* wo = (const float*)d_in[2];   // [512,512]
  float* out = (float*)d_out;                // [4096,16,512] f32

  // ws layout (ushort elems): xb | wqt | wot | qkv ; attn ALIASES xb (dead then).
  unsigned short* xb   = (unsigned short*)d_ws;
  unsigned short* wqt  = xb  + 33554432;   // 65536*512
  unsigned short* wot  = wqt + 786432;     // 1536*512
  unsigned short* qkv  = wot + 262144;     // 512*512
  unsigned short* attn = xb;               // reuse: xb dead after gemm_qkv_k

  conv_x_k  <<<16384, 256, 0, stream>>>(x, xb);
  conv_w_k  <<<4096,  256, 0, stream>>>(wq, wo, wqt, wot);
  gemm_qkv_k<<<6144,  256, 0, stream>>>(xb, wqt, qkv);
  attn_k    <<<8192,  256, 0, stream>>>(qkv, attn);
  gemm_out_k<<<2048,  256, 0, stream>>>(attn, wot, out);
}